// Round 1
// 968.936 us; speedup vs baseline: 1.0219x; 1.0219x over previous
//
#include <hip/hip_runtime.h>
#include <stdint.h>

#define D      2048
#define KSEL   512
#define CHUNKS 8     // D / (64 lanes * 4 elems)

typedef float    f4 __attribute__((ext_vector_type(4)));
typedef unsigned u4 __attribute__((ext_vector_type(4)));

// ---- wave(64)-level reductions, no LDS ----
__device__ __forceinline__ int wave_sum_i(int v) {
    #pragma unroll
    for (int o = 32; o > 0; o >>= 1) v += __shfl_xor(v, o, 64);
    return v;
}
__device__ __forceinline__ unsigned wave_min_u(unsigned v) {
    #pragma unroll
    for (int o = 32; o > 0; o >>= 1) { unsigned t = __shfl_xor((int)v, o, 64); v = (t < v) ? t : v; }
    return v;
}
__device__ __forceinline__ unsigned wave_max_u(unsigned v) {
    #pragma unroll
    for (int o = 32; o > 0; o >>= 1) { unsigned t = __shfl_xor((int)v, o, 64); v = (t > v) ? t : v; }
    return v;
}

__device__ __forceinline__ int count_ge(const u4* r, unsigned p) {
    int c = 0;
    #pragma unroll
    for (int i = 0; i < CHUNKS; ++i) {
        c += (int)(r[i][0] >= p) + (int)(r[i][1] >= p) + (int)(r[i][2] >= p) + (int)(r[i][3] >= p);
    }
    return wave_sum_i(c);
}
__device__ __forceinline__ int count_eq(const u4* r, unsigned p) {
    int c = 0;
    #pragma unroll
    for (int i = 0; i < CHUNKS; ++i) {
        c += (int)(r[i][0] == p) + (int)(r[i][1] == p) + (int)(r[i][2] == p) + (int)(r[i][3] == p);
    }
    return wave_sum_i(c);
}
__device__ __forceinline__ unsigned min_ge(const u4* r, unsigned lo) {
    unsigned m = 0xFFFFFFFFu;
    #pragma unroll
    for (int i = 0; i < CHUNKS; ++i) {
        unsigned a;
        a = r[i][0]; if (a >= lo && a < m) m = a;
        a = r[i][1]; if (a >= lo && a < m) m = a;
        a = r[i][2]; if (a >= lo && a < m) m = a;
        a = r[i][3]; if (a >= lo && a < m) m = a;
    }
    return wave_min_u(m);
}
__device__ __forceinline__ unsigned max_in(const u4* r, unsigned lo, unsigned hi) {
    unsigned m = 0u;
    #pragma unroll
    for (int i = 0; i < CHUNKS; ++i) {
        unsigned a;
        a = r[i][0]; if (a >= lo && a <= hi && a > m) m = a;
        a = r[i][1]; if (a >= lo && a <= hi && a > m) m = a;
        a = r[i][2]; if (a >= lo && a <= hi && a > m) m = a;
        a = r[i][3]; if (a >= lo && a <= hi && a > m) m = a;
    }
    return wave_max_u(m);
}

// block=256: 4 waves (rows) per block. min 6 waves/EU -> VGPR cap ~85,
// 24 waves/CU (2x the previous ~12) so memory latency + selection-phase
// bubbles are hidden by TLP. Payload registers: rb[8]=32 + 2-deep d/n
// pipeline=16 + temps ~= 70.
__global__ __launch_bounds__(256, 6)
void BaseObservationModel_42923903156755_kernel(
    const float* __restrict__ data, const float* __restrict__ noise,
    const float* __restrict__ rand_vals, float* __restrict__ out,
    long long n_elems)
{
    const int lane = threadIdx.x & 63;
    const long long rows = n_elems / D;
    const long long row  = (long long)blockIdx.x * 4 + (threadIdx.x >> 6);
    if (row >= rows) return;
    const long long base = row * D;

    const u4* rp = (const u4*)(rand_vals + base);
    const f4* dp = (const f4*)(data + base);
    const f4* np = (const f4*)(noise + base);
    f4* op = (f4*)(out + base);             // masked
    f4* ip = (f4*)(out + n_elems + base);   // mask_inverse

    // rand bits: needed for selection AND the final mask compare -> keep live.
    u4 rb[CHUNKS];
    #pragma unroll
    for (int i = 0; i < CHUNKS; ++i) rb[i] = __builtin_nontemporal_load(rp + i * 64 + lane);

    // 2-deep prefetch of the data/noise stream; issued before selection so
    // these are in flight while this wave runs the binsearch.
    f4 d0 = __builtin_nontemporal_load(dp + 0 * 64 + lane);
    f4 n0 = __builtin_nontemporal_load(np + 0 * 64 + lane);
    f4 d1 = __builtin_nontemporal_load(dp + 1 * 64 + lane);
    f4 n1 = __builtin_nontemporal_load(np + 1 * 64 + lane);

    // ---- exact K-th largest of row's rand bits (uint order == float order, all in [0,1)) ----
    // invariants: cnt_ge(lo) >= K,  cnt_ge(hi+1) < K,  answer T in [lo, hi]
    unsigned lo = 0u, hi = 0x3F7FFFFFu;
    int cnt_lo = D, cnt_hi1 = 0;
    unsigned T; int need2; int cnteq;
    int it = 0;
    for (;;) {
        if (cnt_lo == KSEL) {            // top-K set is exactly {v >= lo}
            T = min_ge(rb, lo);
            cnteq = count_eq(rb, T);
            need2 = cnteq;               // all equals masked
            break;
        }
        if (cnt_hi1 == KSEL - 1) {       // exactly one more needed: T = max in [lo,hi]
            T = max_in(rb, lo, hi);
            cnteq = count_eq(rb, T);
            need2 = 1;
            break;
        }
        if (lo == hi) {
            T = lo;
            cnteq = cnt_lo - cnt_hi1;
            need2 = KSEL - cnt_hi1;
            break;
        }
        unsigned mid;
        if (it & 1) {                    // guaranteed-progress bisection
            mid = lo + ((hi - lo + 1) >> 1);
        } else {                         // interpolation in value space (uniform dist)
            float lof = __uint_as_float(lo);
            float hif = __uint_as_float(hi + 1);
            float frac = (float)(cnt_lo - KSEL) / (float)(cnt_lo - cnt_hi1);
            float mf = lof + frac * (hif - lof);
            mid = __float_as_uint(mf);
            if (mid < lo + 1) mid = lo + 1;
            if (mid > hi)     mid = hi;
        }
        int c = count_ge(rb, mid);
        if (c >= KSEL) { lo = mid; cnt_lo = c; }
        else           { hi = mid - 1; cnt_hi1 = c; }
        ++it;
    }

    const bool fast = (need2 == cnteq);  // common case: all elements == T are masked
    int rank_base = 0;                   // (rare path) #equals in earlier chunks, wave-uniform

    #pragma unroll
    for (int i = 0; i < CHUNKS; ++i) {
        // prefetch chunk i+2 (compile-time guarded; loop is fully unrolled)
        f4 dn, nn;
        if (i + 2 < CHUNKS) {
            dn = __builtin_nontemporal_load(dp + (i + 2) * 64 + lane);
            nn = __builtin_nontemporal_load(np + (i + 2) * 64 + lane);
        }

        const u4 rv = rb[i];
        bool m0, m1, m2, m3;
        if (fast) {
            m0 = rv[0] >= T; m1 = rv[1] >= T; m2 = rv[2] >= T; m3 = rv[3] >= T;
        } else {
            // rank equals by global index (i-major, then lane, then j) — stable lower-index-first
            const bool e0 = (rv[0] == T), e1 = (rv[1] == T), e2 = (rv[2] == T), e3 = (rv[3] == T);
            int myc = (int)e0 + (int)e1 + (int)e2 + (int)e3;
            int inc = myc;
            #pragma unroll
            for (int o = 1; o < 64; o <<= 1) {
                int t = __shfl_up(inc, o, 64);
                if (lane >= o) inc += t;
            }
            int r = rank_base + inc - myc;   // exclusive prefix over lanes
            m0 = (rv[0] > T) || (e0 && r < need2); r += (int)e0;
            m1 = (rv[1] > T) || (e1 && r < need2); r += (int)e1;
            m2 = (rv[2] > T) || (e2 && r < need2); r += (int)e2;
            m3 = (rv[3] > T) || (e3 && r < need2); r += (int)e3;
            rank_base += __shfl(inc, 63, 64);
        }

        const f4 d = d0, n = n0;
        f4 o4, i4;
        o4[0] = m0 ? 0.0f : fmaf(0.1f, n[0], d[0]);
        o4[1] = m1 ? 0.0f : fmaf(0.1f, n[1], d[1]);
        o4[2] = m2 ? 0.0f : fmaf(0.1f, n[2], d[2]);
        o4[3] = m3 ? 0.0f : fmaf(0.1f, n[3], d[3]);
        i4[0] = m0 ? 0.0f : 1.0f;
        i4[1] = m1 ? 0.0f : 1.0f;
        i4[2] = m2 ? 0.0f : 1.0f;
        i4[3] = m3 ? 0.0f : 1.0f;
        __builtin_nontemporal_store(o4, op + i * 64 + lane);
        __builtin_nontemporal_store(i4, ip + i * 64 + lane);

        // rotate pipeline
        d0 = d1; n0 = n1;
        if (i + 2 < CHUNKS) { d1 = dn; n1 = nn; }
    }
}

extern "C" void kernel_launch(void* const* d_in, const int* in_sizes, int n_in,
                              void* d_out, int out_size, void* d_ws, size_t ws_size,
                              hipStream_t stream) {
    const float* data      = (const float*)d_in[0];
    const float* noise     = (const float*)d_in[1];
    const float* rand_vals = (const float*)d_in[2];
    float* out = (float*)d_out;
    const long long n = (long long)in_sizes[0];       // 32*1024*2048 = 67108864
    const long long rows = n / D;                     // 32768
    const int blocks = (int)((rows + 3) / 4);         // 4 waves (rows) per 256-thread block
    BaseObservationModel_42923903156755_kernel<<<blocks, 256, 0, stream>>>(
        data, noise, rand_vals, out, n);
}